// Round 1
// baseline (989.853 us; speedup 1.0000x reference)
//
#include <hip/hip_runtime.h>

#define N_OPE 2048
#define N_MAC 1024
#define DIM   64
#define KOUT  128
#define NB    32

typedef __attribute__((ext_vector_type(8))) short short8;
typedef __attribute__((ext_vector_type(4))) float floatx4;

static __device__ __forceinline__ unsigned short f2bf(float f) {
    unsigned int u = __builtin_bit_cast(unsigned int, f);
    u += 0x7fffu + ((u >> 16) & 1u);   // round-to-nearest-even
    return (unsigned short)(u >> 16);
}

// ---------------- kernel 1: h_ope (transposed bf16) + attn_ope ----------------
// lane = one (b,o) row; weights are wave-uniform -> scalar loads; no LDS.
__global__ __launch_bounds__(256) void k_ope(const float* __restrict__ feat,
        const float* __restrict__ w, const float* __restrict__ alpha,
        unsigned short* __restrict__ h_t, float* __restrict__ attn)
{
    int wid = threadIdx.x >> 6, lane = threadIdx.x & 63;
    int R = (blockIdx.x * 4 + wid) * 64 + lane;          // 0..65535
    int b = R >> 11, o = R & (N_OPE - 1);
    const float* fr = feat + (size_t)R * DIM;
    float f[DIM];
    #pragma unroll
    for (int d = 0; d < DIM; d += 4) {
        float4 v = *(const float4*)(fr + d);
        f[d] = v.x; f[d+1] = v.y; f[d+2] = v.z; f[d+3] = v.w;
    }
    unsigned short* htb = h_t + ((size_t)b * KOUT) * N_OPE + o;
    float at = 0.f;
    for (int k = 0; k < KOUT; ++k) {
        const float* wk = w + k * DIM;                   // uniform -> s_load
        float a0 = 0.f, a1 = 0.f, a2 = 0.f, a3 = 0.f;
        #pragma unroll
        for (int d = 0; d < DIM; d += 4) {
            a0 = fmaf(f[d],   wk[d],   a0);
            a1 = fmaf(f[d+1], wk[d+1], a1);
            a2 = fmaf(f[d+2], wk[d+2], a2);
            a3 = fmaf(f[d+3], wk[d+3], a3);
        }
        float acc = (a0 + a1) + (a2 + a3);
        at = fmaf(acc, alpha[k], at);
        htb[(size_t)k * N_OPE] = f2bf(acc);              // h_t[b][k][o], 128B/wave contiguous
    }
    attn[R] = at;
}

// ---------------- kernel 2: attn_mac + h_res (fp32) ----------------
__global__ __launch_bounds__(256) void k_mac(const float* __restrict__ feat,
        const float* __restrict__ wm, const float* __restrict__ wr,
        const float* __restrict__ alpha,
        float* __restrict__ attn, float* __restrict__ h_res)
{
    int wid = threadIdx.x >> 6, lane = threadIdx.x & 63;
    int R = (blockIdx.x * 4 + wid) * 64 + lane;          // 0..32767
    const float* fr = feat + (size_t)R * DIM;
    float f[DIM];
    #pragma unroll
    for (int d = 0; d < DIM; d += 4) {
        float4 v = *(const float4*)(fr + d);
        f[d] = v.x; f[d+1] = v.y; f[d+2] = v.z; f[d+3] = v.w;
    }
    float* hrb = h_res + (size_t)R * KOUT;
    float at = 0.f;
    for (int kc = 0; kc < KOUT; kc += 16) {              // 16-chunks -> 64B/lane stores
        float hr[16];
        #pragma unroll 4
        for (int kk = 0; kk < 16; ++kk) {
            int k = kc + kk;
            const float* wmk = wm + k * DIM;
            const float* wrk = wr + k * DIM;
            float m0 = 0.f, m1 = 0.f, r0 = 0.f, r1 = 0.f;
            #pragma unroll
            for (int d = 0; d < DIM; d += 2) {
                m0 = fmaf(f[d],   wmk[d],   m0);
                m1 = fmaf(f[d+1], wmk[d+1], m1);
                r0 = fmaf(f[d],   wrk[d],   r0);
                r1 = fmaf(f[d+1], wrk[d+1], r1);
            }
            at = fmaf(m0 + m1, alpha[k], at);
            hr[kk] = r0 + r1;
        }
        #pragma unroll
        for (int kk = 0; kk < 16; kk += 4)
            *(float4*)(hrb + kc + kk) = make_float4(hr[kk], hr[kk+1], hr[kk+2], hr[kk+3]);
    }
    attn[R] = at;
}

// ---------------- kernel 3: fused mask->softmax-weight->MFMA GEMM ----------------
// 1 wave/block. GEMM: M=32 machines, N=128 out-dim, K=2048 operations.
// A[m][o] = exp(masked lrelu(ao[o]+am[m])) built IN REGISTERS in A-fragment layout
// (m=lane&15, o=quad*8+j) -> mask loads coalesce to whole 64B lines, read once.
__global__ __launch_bounds__(64) void k_attn(const int* __restrict__ adj,
        const int* __restrict__ bidx,
        const unsigned short* __restrict__ h_t,
        const float* __restrict__ attn_ope, const float* __restrict__ attn_mac,
        const float* __restrict__ h_res, float* __restrict__ out)
{
    int b  = blockIdx.y;
    int m0 = blockIdx.x * 32;
    int lane = threadIdx.x;
    int L = lane & 15, q = lane >> 4;
    const int* adjt = adj + (size_t)bidx[b] * N_OPE * N_MAC;
    const unsigned short* htb = h_t + (size_t)b * KOUT * N_OPE;
    const float* aob = attn_ope + b * N_OPE;
    float am0 = attn_mac[b * N_MAC + m0 + L];
    float am1 = attn_mac[b * N_MAC + m0 + 16 + L];

    floatx4 C0[8], C1[8];
    #pragma unroll
    for (int i = 0; i < 8; ++i) { C0[i] = (floatx4)0.f; C1[i] = (floatx4)0.f; }
    float den0 = 0.f, den1 = 0.f;

    for (int o0 = 0; o0 < N_OPE; o0 += 32) {
        int ob = o0 + q * 8;
        float4 aoA = *(const float4*)(aob + ob);
        float4 aoB = *(const float4*)(aob + ob + 4);
        float ao[8] = {aoA.x, aoA.y, aoA.z, aoA.w, aoB.x, aoB.y, aoB.z, aoB.w};

        short8 Bf[8];
        #pragma unroll
        for (int nf = 0; nf < 8; ++nf)     // B[k=o][n]: 16B contiguous per lane
            Bf[nf] = *(const short8*)(htb + (size_t)(nf * 16 + L) * N_OPE + ob);

        int mk0[8], mk1[8];
        #pragma unroll
        for (int j = 0; j < 8; ++j) {
            mk0[j] = adjt[(size_t)(ob + j) * N_MAC + m0 + L];
            mk1[j] = adjt[(size_t)(ob + j) * N_MAC + m0 + 16 + L];
        }

        short8 A0, A1;
        #pragma unroll
        for (int j = 0; j < 8; ++j) {
            float e0 = ao[j] + am0;
            e0 = fmaxf(e0, 0.2f * e0);                 // leaky relu
            float w0 = (mk0[j] == 1) ? __expf(e0) : 0.f;
            den0 += w0;
            A0[j] = (short)f2bf(w0);
            float e1 = ao[j] + am1;
            e1 = fmaxf(e1, 0.2f * e1);
            float w1 = (mk1[j] == 1) ? __expf(e1) : 0.f;
            den1 += w1;
            A1[j] = (short)f2bf(w1);
        }

        #pragma unroll
        for (int nf = 0; nf < 8; ++nf) {
            C0[nf] = __builtin_amdgcn_mfma_f32_16x16x32_bf16(A0, Bf[nf], C0[nf], 0, 0, 0);
            C1[nf] = __builtin_amdgcn_mfma_f32_16x16x32_bf16(A1, Bf[nf], C1[nf], 0, 0, 0);
        }
    }

    // denominator: A-layout partials live per (quad) -> reduce across quads
    den0 += __shfl_xor(den0, 16); den0 += __shfl_xor(den0, 32);
    den1 += __shfl_xor(den1, 16); den1 += __shfl_xor(den1, 32);
    __shared__ float dls[32];
    if (q == 0) { dls[L] = den0; dls[16 + L] = den1; }
    __syncthreads();

    // epilogue: C/D layout row = q*4+r, col = L
    #pragma unroll
    for (int fm = 0; fm < 2; ++fm) {
        const floatx4* Cf = fm ? C1 : C0;
        #pragma unroll
        for (int r = 0; r < 4; ++r) {
            int m = fm * 16 + q * 4 + r;
            float inv = 1.0f / dls[m];
            size_t base = ((size_t)b * N_MAC + m0 + m) * KOUT;
            #pragma unroll
            for (int nf = 0; nf < 8; ++nf) {
                int n = nf * 16 + L;
                out[base + n] = Cf[nf][r] * inv + h_res[base + n];
            }
        }
    }
}

extern "C" void kernel_launch(void* const* d_in, const int* in_sizes, int n_in,
                              void* d_out, int out_size, void* d_ws, size_t ws_size,
                              hipStream_t stream) {
    const int*   adj       = (const int*)d_in[0];
    const int*   bidx      = (const int*)d_in[1];
    const float* feat_ope  = (const float*)d_in[2];
    const float* feat_mac  = (const float*)d_in[3];
    const float* ope_w     = (const float*)d_in[4];
    const float* mac_w     = (const float*)d_in[5];
    const float* ope_alpha = (const float*)d_in[6];
    const float* mac_alpha = (const float*)d_in[7];
    const float* res_w     = (const float*)d_in[8];
    float* out = (float*)d_out;

    char* ws = (char*)d_ws;
    unsigned short* h_t   = (unsigned short*)ws;                        // 16 MiB bf16 [B][128][2048]
    float* attn_ope = (float*)(ws + (size_t)(16 << 20));                // 256 KiB
    float* attn_mac = (float*)(ws + (size_t)(16 << 20) + (256 << 10));  // 128 KiB
    float* h_res    = (float*)(ws + (size_t)(17 << 20));                // 16 MiB f32 [B][1024][128]

    k_ope<<<256, 256, 0, stream>>>(feat_ope, ope_w, ope_alpha, h_t, attn_ope);
    k_mac<<<128, 256, 0, stream>>>(feat_mac, mac_w, res_w, mac_alpha, attn_mac, h_res);
    k_attn<<<dim3(N_MAC / 32, NB), 64, 0, stream>>>(adj, bidx, h_t, attn_ope,
                                                    attn_mac, h_res, out);
}

// Round 2
// 733.426 us; speedup vs baseline: 1.3496x; 1.3496x over previous
//
#include <hip/hip_runtime.h>

#define N_OPE 2048
#define N_MAC 1024
#define DIM   64
#define KOUT  128
#define NB    32

typedef __attribute__((ext_vector_type(8))) short short8;
typedef __attribute__((ext_vector_type(4))) float floatx4;

static __device__ __forceinline__ unsigned short f2bf(float f) {
    unsigned int u = __builtin_bit_cast(unsigned int, f);
    u += 0x7fffu + ((u >> 16) & 1u);   // round-to-nearest-even
    return (unsigned short)(u >> 16);
}
static __device__ __forceinline__ float bf2f(unsigned short h) {
    unsigned int u = ((unsigned int)h) << 16;
    return __builtin_bit_cast(float, u);
}

// ---------------- kernel 0: wa[d] = sum_n w[n][d] * alpha[n] (reassociated attn) ----
__global__ void k_wa(const float* __restrict__ ow, const float* __restrict__ mw,
                     const float* __restrict__ oa, const float* __restrict__ ma,
                     float* __restrict__ wa)
{
    int t = threadIdx.x;                       // 128 threads
    const float* w = (t < 64) ? ow : mw;
    const float* a = (t < 64) ? oa : ma;
    int d = t & 63;
    float s = 0.f;
    #pragma unroll 8
    for (int n = 0; n < KOUT; ++n) s = fmaf(w[n * DIM + d], a[n], s);
    wa[t] = s;
}

// ---------------- kernel 1: h_ope via 3-term bf16 MFMA -> h_t (transposed bf16), attn_ope ----
// wave handles 32 rows x 128 n x K=64. Block = 4 waves = 128 rows.
__global__ __launch_bounds__(256, 2) void k_ope(const float* __restrict__ feat,
        const float* __restrict__ w, const float* __restrict__ wa,
        unsigned short* __restrict__ h_t, float* __restrict__ attn)
{
    int wid = threadIdx.x >> 6, lane = threadIdx.x & 63;
    int L = lane & 15, q = lane >> 4;
    int base = blockIdx.x * 128 + wid * 32;           // row base for this wave
    int b = base >> 11;                                // rows per batch = 2048
    int o0w = base & (N_OPE - 1);

    // ---- load A (feat rows) in fragment layout: A[m=L][k=q*8+j], ks in {0,32}
    float fA[2][2][8];                                 // [mf][ks][j]
    #pragma unroll
    for (int mf = 0; mf < 2; ++mf) {
        const float* fr = feat + (size_t)(base + mf * 16 + L) * DIM + q * 8;
        #pragma unroll
        for (int ks = 0; ks < 2; ++ks) {
            float4 v0 = *(const float4*)(fr + ks * 32);
            float4 v1 = *(const float4*)(fr + ks * 32 + 4);
            fA[mf][ks][0] = v0.x; fA[mf][ks][1] = v0.y; fA[mf][ks][2] = v0.z; fA[mf][ks][3] = v0.w;
            fA[mf][ks][4] = v1.x; fA[mf][ks][5] = v1.y; fA[mf][ks][6] = v1.z; fA[mf][ks][7] = v1.w;
        }
    }

    // ---- attn_ope = feat . wa  (fp32, reassociated)
    float wav[2][8];
    #pragma unroll
    for (int ks = 0; ks < 2; ++ks) {
        float4 w0 = *(const float4*)(wa + ks * 32 + q * 8);
        float4 w1 = *(const float4*)(wa + ks * 32 + q * 8 + 4);
        wav[ks][0] = w0.x; wav[ks][1] = w0.y; wav[ks][2] = w0.z; wav[ks][3] = w0.w;
        wav[ks][4] = w1.x; wav[ks][5] = w1.y; wav[ks][6] = w1.z; wav[ks][7] = w1.w;
    }
    float part[2] = {0.f, 0.f};
    #pragma unroll
    for (int mf = 0; mf < 2; ++mf)
        #pragma unroll
        for (int ks = 0; ks < 2; ++ks)
            #pragma unroll
            for (int j = 0; j < 8; ++j)
                part[mf] = fmaf(fA[mf][ks][j], wav[ks][j], part[mf]);
    part[0] += __shfl_xor(part[0], 16); part[0] += __shfl_xor(part[0], 32);
    part[1] += __shfl_xor(part[1], 16); part[1] += __shfl_xor(part[1], 32);
    if (q == 0) {
        attn[base + L]      = part[0];
        attn[base + 16 + L] = part[1];
    }

    // ---- split A into hi/lo bf16
    short8 Ah[2][2], Al[2][2];
    #pragma unroll
    for (int mf = 0; mf < 2; ++mf)
        #pragma unroll
        for (int ks = 0; ks < 2; ++ks)
            #pragma unroll
            for (int j = 0; j < 8; ++j) {
                float x = fA[mf][ks][j];
                unsigned short h = f2bf(x);
                Ah[mf][ks][j] = (short)h;
                Al[mf][ks][j] = (short)f2bf(x - bf2f(h));
            }

    floatx4 C[2][8];
    #pragma unroll
    for (int mf = 0; mf < 2; ++mf)
        #pragma unroll
        for (int nf = 0; nf < 8; ++nf) C[mf][nf] = (floatx4)0.f;

    #pragma unroll
    for (int ks = 0; ks < 2; ++ks) {
        #pragma unroll
        for (int nf = 0; nf < 8; ++nf) {
            // B[k][n] = w[n][k]; lane: n = nf*16+L, k = ks*32 + q*8 + j (contiguous)
            const float* wp = w + (size_t)(nf * 16 + L) * DIM + ks * 32 + q * 8;
            float4 u0 = *(const float4*)(wp);
            float4 u1 = *(const float4*)(wp + 4);
            float bw[8] = {u0.x, u0.y, u0.z, u0.w, u1.x, u1.y, u1.z, u1.w};
            short8 Bh, Bl;
            #pragma unroll
            for (int j = 0; j < 8; ++j) {
                unsigned short h = f2bf(bw[j]);
                Bh[j] = (short)h;
                Bl[j] = (short)f2bf(bw[j] - bf2f(h));
            }
            #pragma unroll
            for (int mf = 0; mf < 2; ++mf) {
                C[mf][nf] = __builtin_amdgcn_mfma_f32_16x16x32_bf16(Ah[mf][ks], Bh, C[mf][nf], 0, 0, 0);
                C[mf][nf] = __builtin_amdgcn_mfma_f32_16x16x32_bf16(Al[mf][ks], Bh, C[mf][nf], 0, 0, 0);
                C[mf][nf] = __builtin_amdgcn_mfma_f32_16x16x32_bf16(Ah[mf][ks], Bl, C[mf][nf], 0, 0, 0);
            }
        }
    }

    // ---- transpose via per-wave LDS slice, store h_t[b][n][o] coalesced
    __shared__ unsigned short T[4][128 * 34];          // stride 34 shorts: conflict-safe
    #pragma unroll
    for (int mf = 0; mf < 2; ++mf)
        #pragma unroll
        for (int nf = 0; nf < 8; ++nf)
            #pragma unroll
            for (int r = 0; r < 4; ++r)
                T[wid][(nf * 16 + L) * 34 + mf * 16 + q * 4 + r] = f2bf(C[mf][nf][r]);
    __syncthreads();
    unsigned short* htb = h_t + (size_t)b * KOUT * N_OPE;
    #pragma unroll 4
    for (int t = 0; t < 32; ++t) {
        int n = t * 4 + q;                              // 4 n-rows per instruction
        ushort2 v = *(const ushort2*)&T[wid][n * 34 + 2 * L];
        *(ushort2*)(htb + (size_t)n * N_OPE + o0w + 2 * L) = v;
    }
}

// ---------------- kernel 2: h_res via 3-term bf16 MFMA (natural layout), attn_mac ----
__global__ __launch_bounds__(256, 2) void k_mac(const float* __restrict__ feat,
        const float* __restrict__ w, const float* __restrict__ wa,
        float* __restrict__ h_res, float* __restrict__ attn)
{
    int wid = threadIdx.x >> 6, lane = threadIdx.x & 63;
    int L = lane & 15, q = lane >> 4;
    int base = blockIdx.x * 128 + wid * 32;            // row base (32768 rows total)

    float fA[2][2][8];
    #pragma unroll
    for (int mf = 0; mf < 2; ++mf) {
        const float* fr = feat + (size_t)(base + mf * 16 + L) * DIM + q * 8;
        #pragma unroll
        for (int ks = 0; ks < 2; ++ks) {
            float4 v0 = *(const float4*)(fr + ks * 32);
            float4 v1 = *(const float4*)(fr + ks * 32 + 4);
            fA[mf][ks][0] = v0.x; fA[mf][ks][1] = v0.y; fA[mf][ks][2] = v0.z; fA[mf][ks][3] = v0.w;
            fA[mf][ks][4] = v1.x; fA[mf][ks][5] = v1.y; fA[mf][ks][6] = v1.z; fA[mf][ks][7] = v1.w;
        }
    }

    float wav[2][8];
    #pragma unroll
    for (int ks = 0; ks < 2; ++ks) {
        float4 w0 = *(const float4*)(wa + ks * 32 + q * 8);
        float4 w1 = *(const float4*)(wa + ks * 32 + q * 8 + 4);
        wav[ks][0] = w0.x; wav[ks][1] = w0.y; wav[ks][2] = w0.z; wav[ks][3] = w0.w;
        wav[ks][4] = w1.x; wav[ks][5] = w1.y; wav[ks][6] = w1.z; wav[ks][7] = w1.w;
    }
    float part[2] = {0.f, 0.f};
    #pragma unroll
    for (int mf = 0; mf < 2; ++mf)
        #pragma unroll
        for (int ks = 0; ks < 2; ++ks)
            #pragma unroll
            for (int j = 0; j < 8; ++j)
                part[mf] = fmaf(fA[mf][ks][j], wav[ks][j], part[mf]);
    part[0] += __shfl_xor(part[0], 16); part[0] += __shfl_xor(part[0], 32);
    part[1] += __shfl_xor(part[1], 16); part[1] += __shfl_xor(part[1], 32);
    if (q == 0) {
        attn[base + L]      = part[0];
        attn[base + 16 + L] = part[1];
    }

    short8 Ah[2][2], Al[2][2];
    #pragma unroll
    for (int mf = 0; mf < 2; ++mf)
        #pragma unroll
        for (int ks = 0; ks < 2; ++ks)
            #pragma unroll
            for (int j = 0; j < 8; ++j) {
                float x = fA[mf][ks][j];
                unsigned short h = f2bf(x);
                Ah[mf][ks][j] = (short)h;
                Al[mf][ks][j] = (short)f2bf(x - bf2f(h));
            }

    floatx4 C[2][8];
    #pragma unroll
    for (int mf = 0; mf < 2; ++mf)
        #pragma unroll
        for (int nf = 0; nf < 8; ++nf) C[mf][nf] = (floatx4)0.f;

    #pragma unroll
    for (int ks = 0; ks < 2; ++ks) {
        #pragma unroll
        for (int nf = 0; nf < 8; ++nf) {
            const float* wp = w + (size_t)(nf * 16 + L) * DIM + ks * 32 + q * 8;
            float4 u0 = *(const float4*)(wp);
            float4 u1 = *(const float4*)(wp + 4);
            float bw[8] = {u0.x, u0.y, u0.z, u0.w, u1.x, u1.y, u1.z, u1.w};
            short8 Bh, Bl;
            #pragma unroll
            for (int j = 0; j < 8; ++j) {
                unsigned short h = f2bf(bw[j]);
                Bh[j] = (short)h;
                Bl[j] = (short)f2bf(bw[j] - bf2f(h));
            }
            #pragma unroll
            for (int mf = 0; mf < 2; ++mf) {
                C[mf][nf] = __builtin_amdgcn_mfma_f32_16x16x32_bf16(Ah[mf][ks], Bh, C[mf][nf], 0, 0, 0);
                C[mf][nf] = __builtin_amdgcn_mfma_f32_16x16x32_bf16(Al[mf][ks], Bh, C[mf][nf], 0, 0, 0);
                C[mf][nf] = __builtin_amdgcn_mfma_f32_16x16x32_bf16(Ah[mf][ks], Bl, C[mf][nf], 0, 0, 0);
            }
        }
    }

    // store h_res[row][n] directly from C/D layout (row=q*4+r, col=L)
    #pragma unroll
    for (int mf = 0; mf < 2; ++mf)
        #pragma unroll
        for (int nf = 0; nf < 8; ++nf)
            #pragma unroll
            for (int r = 0; r < 4; ++r)
                h_res[(size_t)(base + mf * 16 + q * 4 + r) * KOUT + nf * 16 + L] = C[mf][nf][r];
}

// ---------------- kernel 3: fused mask->softmax->MFMA, 2-wave K-split ----------------
__global__ __launch_bounds__(128) void k_attn(const int* __restrict__ adj,
        const int* __restrict__ bidx,
        const unsigned short* __restrict__ h_t,
        const float* __restrict__ attn_ope, const float* __restrict__ attn_mac,
        const float* __restrict__ h_res, float* __restrict__ out)
{
    int b  = blockIdx.y;
    int m0 = blockIdx.x * 32;
    int wv = threadIdx.x >> 6;                 // K-split wave id (0,1)
    int lane = threadIdx.x & 63;
    int L = lane & 15, q = lane >> 4;
    const int* adjt = adj + (size_t)bidx[b] * N_OPE * N_MAC;
    const unsigned short* htb = h_t + (size_t)b * KOUT * N_OPE;
    const float* aob = attn_ope + b * N_OPE;
    float am0 = attn_mac[b * N_MAC + m0 + L];
    float am1 = attn_mac[b * N_MAC + m0 + 16 + L];

    floatx4 C0[8], C1[8];
    #pragma unroll
    for (int i = 0; i < 8; ++i) { C0[i] = (floatx4)0.f; C1[i] = (floatx4)0.f; }
    float den0 = 0.f, den1 = 0.f;

    int oBeg = wv * (N_OPE / 2), oEnd = oBeg + (N_OPE / 2);
    for (int o0 = oBeg; o0 < oEnd; o0 += 32) {
        int ob = o0 + q * 8;
        float4 aoA = *(const float4*)(aob + ob);
        float4 aoB = *(const float4*)(aob + ob + 4);
        float ao[8] = {aoA.x, aoA.y, aoA.z, aoA.w, aoB.x, aoB.y, aoB.z, aoB.w};

        short8 Bf[8];
        #pragma unroll
        for (int nf = 0; nf < 8; ++nf)
            Bf[nf] = *(const short8*)(htb + (size_t)(nf * 16 + L) * N_OPE + ob);

        int mk0[8], mk1[8];
        #pragma unroll
        for (int j = 0; j < 8; ++j) {
            mk0[j] = adjt[(size_t)(ob + j) * N_MAC + m0 + L];
            mk1[j] = adjt[(size_t)(ob + j) * N_MAC + m0 + 16 + L];
        }

        short8 A0, A1;
        #pragma unroll
        for (int j = 0; j < 8; ++j) {
            float e0 = ao[j] + am0;
            e0 = fmaxf(e0, 0.2f * e0);
            float w0 = (mk0[j] == 1) ? __expf(e0) : 0.f;
            den0 += w0;
            A0[j] = (short)f2bf(w0);
            float e1 = ao[j] + am1;
            e1 = fmaxf(e1, 0.2f * e1);
            float w1 = (mk1[j] == 1) ? __expf(e1) : 0.f;
            den1 += w1;
            A1[j] = (short)f2bf(w1);
        }

        #pragma unroll
        for (int nf = 0; nf < 8; ++nf) {
            C0[nf] = __builtin_amdgcn_mfma_f32_16x16x32_bf16(A0, Bf[nf], C0[nf], 0, 0, 0);
            C1[nf] = __builtin_amdgcn_mfma_f32_16x16x32_bf16(A1, Bf[nf], C1[nf], 0, 0, 0);
        }
    }

    den0 += __shfl_xor(den0, 16); den0 += __shfl_xor(den0, 32);
    den1 += __shfl_xor(den1, 16); den1 += __shfl_xor(den1, 32);

    __shared__ float CS[32 * 132];             // wave1's partial C (stride 132: 2-way max)
    __shared__ float DS[2][32];
    if (wv == 1) {
        #pragma unroll
        for (int fm = 0; fm < 2; ++fm) {
            const floatx4* Cf = fm ? C1 : C0;
            #pragma unroll
            for (int nf = 0; nf < 8; ++nf)
                #pragma unroll
                for (int r = 0; r < 4; ++r)
                    CS[(fm * 16 + q * 4 + r) * 132 + nf * 16 + L] = Cf[nf][r];
        }
        if (q == 0) { DS[1][L] = den0; DS[1][16 + L] = den1; }
    } else {
        if (q == 0) { DS[0][L] = den0; DS[0][16 + L] = den1; }
    }
    __syncthreads();

    if (wv == 0) {
        #pragma unroll
        for (int fm = 0; fm < 2; ++fm) {
            const floatx4* Cf = fm ? C1 : C0;
            #pragma unroll
            for (int r = 0; r < 4; ++r) {
                int m = fm * 16 + q * 4 + r;
                float inv = 1.0f / (DS[0][m] + DS[1][m]);
                size_t obase = ((size_t)b * N_MAC + m0 + m) * KOUT;
                #pragma unroll
                for (int nf = 0; nf < 8; ++nf) {
                    int n = nf * 16 + L;
                    float v = Cf[nf][r] + CS[m * 132 + n];
                    out[obase + n] = v * inv + h_res[obase + n];
                }
            }
        }
    }
}

extern "C" void kernel_launch(void* const* d_in, const int* in_sizes, int n_in,
                              void* d_out, int out_size, void* d_ws, size_t ws_size,
                              hipStream_t stream) {
    const int*   adj       = (const int*)d_in[0];
    const int*   bidx      = (const int*)d_in[1];
    const float* feat_ope  = (const float*)d_in[2];
    const float* feat_mac  = (const float*)d_in[3];
    const float* ope_w     = (const float*)d_in[4];
    const float* mac_w     = (const float*)d_in[5];
    const float* ope_alpha = (const float*)d_in[6];
    const float* mac_alpha = (const float*)d_in[7];
    const float* res_w     = (const float*)d_in[8];
    float* out = (float*)d_out;

    char* ws = (char*)d_ws;
    unsigned short* h_t = (unsigned short*)ws;                           // 16 MiB
    float* attn_ope = (float*)(ws + (size_t)(16 << 20));                 // 256 KiB
    float* attn_mac = (float*)(ws + (size_t)(16 << 20) + (256 << 10));   // 128 KiB
    float* wa       = (float*)(ws + (size_t)(16 << 20) + (384 << 10));   // 512 B
    float* h_res    = (float*)(ws + (size_t)(17 << 20));                 // 16 MiB

    k_wa<<<1, 128, 0, stream>>>(ope_w, mac_w, ope_alpha, mac_alpha, wa);
    k_ope<<<512, 256, 0, stream>>>(feat_ope, ope_w, wa, h_t, attn_ope);
    k_mac<<<256, 256, 0, stream>>>(feat_mac, res_w, wa + 64, h_res, attn_mac);
    k_attn<<<dim3(N_MAC / 32, NB), 128, 0, stream>>>(adj, bidx, h_t, attn_ope,
                                                     attn_mac, h_res, out);
}

// Round 3
// 718.494 us; speedup vs baseline: 1.3777x; 1.0208x over previous
//
#include <hip/hip_runtime.h>

#define N_OPE 2048
#define N_MAC 1024
#define DIM   64
#define KOUT  128
#define NB    32

typedef __attribute__((ext_vector_type(8))) short short8;
typedef __attribute__((ext_vector_type(4))) float floatx4;

static __device__ __forceinline__ unsigned short f2bf(float f) {
    unsigned int u = __builtin_bit_cast(unsigned int, f);
    u += 0x7fffu + ((u >> 16) & 1u);   // round-to-nearest-even
    return (unsigned short)(u >> 16);
}
static __device__ __forceinline__ float bf2f(unsigned short h) {
    unsigned int u = ((unsigned int)h) << 16;
    return __builtin_bit_cast(float, u);
}

// ---------------- kernel 1: h_ope via 3-term bf16 MFMA -> h_t (transposed bf16),
//                  plus pq[o] = (exp(attn_ope), exp(0.2*attn_ope)) from exact C.alpha ----
__global__ __launch_bounds__(256, 2) void k_ope(const float* __restrict__ feat,
        const float* __restrict__ w, const float* __restrict__ alpha,
        unsigned short* __restrict__ h_t, float2* __restrict__ pq)
{
    int wid = threadIdx.x >> 6, lane = threadIdx.x & 63;
    int L = lane & 15, q = lane >> 4;
    int base = blockIdx.x * 128 + wid * 32;           // row base for this wave
    int b = base >> 11;                                // rows per batch = 2048
    int o0w = base & (N_OPE - 1);

    // ---- load A (feat rows) in fragment layout: A[m=L][k=q*8+j], ks in {0,32}
    float fA[2][2][8];                                 // [mf][ks][j]
    #pragma unroll
    for (int mf = 0; mf < 2; ++mf) {
        const float* fr = feat + (size_t)(base + mf * 16 + L) * DIM + q * 8;
        #pragma unroll
        for (int ks = 0; ks < 2; ++ks) {
            float4 v0 = *(const float4*)(fr + ks * 32);
            float4 v1 = *(const float4*)(fr + ks * 32 + 4);
            fA[mf][ks][0] = v0.x; fA[mf][ks][1] = v0.y; fA[mf][ks][2] = v0.z; fA[mf][ks][3] = v0.w;
            fA[mf][ks][4] = v1.x; fA[mf][ks][5] = v1.y; fA[mf][ks][6] = v1.z; fA[mf][ks][7] = v1.w;
        }
    }

    // ---- split A into hi/lo bf16
    short8 Ah[2][2], Al[2][2];
    #pragma unroll
    for (int mf = 0; mf < 2; ++mf)
        #pragma unroll
        for (int ks = 0; ks < 2; ++ks)
            #pragma unroll
            for (int j = 0; j < 8; ++j) {
                float x = fA[mf][ks][j];
                unsigned short h = f2bf(x);
                Ah[mf][ks][j] = (short)h;
                Al[mf][ks][j] = (short)f2bf(x - bf2f(h));
            }

    floatx4 C[2][8];
    #pragma unroll
    for (int mf = 0; mf < 2; ++mf)
        #pragma unroll
        for (int nf = 0; nf < 8; ++nf) C[mf][nf] = (floatx4)0.f;

    #pragma unroll
    for (int ks = 0; ks < 2; ++ks) {
        #pragma unroll
        for (int nf = 0; nf < 8; ++nf) {
            const float* wp = w + (size_t)(nf * 16 + L) * DIM + ks * 32 + q * 8;
            float4 u0 = *(const float4*)(wp);
            float4 u1 = *(const float4*)(wp + 4);
            float bw[8] = {u0.x, u0.y, u0.z, u0.w, u1.x, u1.y, u1.z, u1.w};
            short8 Bh, Bl;
            #pragma unroll
            for (int j = 0; j < 8; ++j) {
                unsigned short h = f2bf(bw[j]);
                Bh[j] = (short)h;
                Bl[j] = (short)f2bf(bw[j] - bf2f(h));
            }
            #pragma unroll
            for (int mf = 0; mf < 2; ++mf) {
                C[mf][nf] = __builtin_amdgcn_mfma_f32_16x16x32_bf16(Ah[mf][ks], Bh, C[mf][nf], 0, 0, 0);
                C[mf][nf] = __builtin_amdgcn_mfma_f32_16x16x32_bf16(Al[mf][ks], Bh, C[mf][nf], 0, 0, 0);
                C[mf][nf] = __builtin_amdgcn_mfma_f32_16x16x32_bf16(Ah[mf][ks], Bl, C[mf][nf], 0, 0, 0);
            }
        }
    }

    // ---- pq from exact fp32 C . alpha (row = mf*16+q*4+r, col = nf*16+L)
    float alf[8];
    #pragma unroll
    for (int nf = 0; nf < 8; ++nf) alf[nf] = alpha[nf * 16 + L];
    #pragma unroll
    for (int mf = 0; mf < 2; ++mf) {
        #pragma unroll
        for (int r = 0; r < 4; ++r) {
            float s = 0.f;
            #pragma unroll
            for (int nf = 0; nf < 8; ++nf) s = fmaf(C[mf][nf][r], alf[nf], s);
            s += __shfl_xor(s, 1); s += __shfl_xor(s, 2);
            s += __shfl_xor(s, 4); s += __shfl_xor(s, 8);
            if (L == 0)
                pq[base + mf * 16 + q * 4 + r] = make_float2(__expf(s), __expf(0.2f * s));
        }
    }

    // ---- transpose via per-wave LDS slice, store h_t[b][n][o] coalesced
    __shared__ unsigned short T[4][128 * 34];          // stride 34 shorts: conflict-safe
    #pragma unroll
    for (int mf = 0; mf < 2; ++mf)
        #pragma unroll
        for (int nf = 0; nf < 8; ++nf)
            #pragma unroll
            for (int r = 0; r < 4; ++r)
                T[wid][(nf * 16 + L) * 34 + mf * 16 + q * 4 + r] = f2bf(C[mf][nf][r]);
    __syncthreads();
    unsigned short* htb = h_t + (size_t)b * KOUT * N_OPE;
    #pragma unroll 4
    for (int t = 0; t < 32; ++t) {
        int n = t * 4 + q;
        ushort2 v = *(const ushort2*)&T[wid][n * 34 + 2 * L];
        *(ushort2*)(htb + (size_t)n * N_OPE + o0w + 2 * L) = v;
    }
}

// ---------------- kernel 2: fully fused attention + h_res ----------------
// 4-wave blocks, 4-way K-split, factorized exp, inline h_res via split MFMA.
__global__ __launch_bounds__(256, 3) void k_attn(const int* __restrict__ adj,
        const int* __restrict__ bidx,
        const unsigned short* __restrict__ h_t,
        const float2* __restrict__ pq,
        const float* __restrict__ feat_mac,
        const float* __restrict__ mac_w, const float* __restrict__ mac_alpha,
        const float* __restrict__ res_w,
        float* __restrict__ out)
{
    int b  = blockIdx.y;
    int m0 = blockIdx.x * 32;
    int t  = threadIdx.x;
    int wv = t >> 6;
    int lane = t & 63;
    int L = lane & 15, q = lane >> 4;

    __shared__ float buf0[32 * 132];
    __shared__ float buf1[32 * 132];
    __shared__ float waS[64];
    __shared__ float amS[32];
    __shared__ float DS[4][32];

    // ---- wa_mac[d] = sum_n mac_w[n][d] * mac_alpha[n] (buf0 as scratch)
    {
        int d = t & 63, seg = t >> 6;
        float p = 0.f;
        #pragma unroll 8
        for (int n = seg * 32; n < seg * 32 + 32; ++n)
            p = fmaf(mac_w[n * DIM + d], mac_alpha[n], p);
        buf0[seg * 64 + d] = p;
    }
    __syncthreads();
    if (t < 64) waS[t] = buf0[t] + buf0[64 + t] + buf0[128 + t] + buf0[192 + t];
    __syncthreads();
    // ---- am[m] = feat_mac[b][m0+m] . waS  (buf1 as scratch)
    {
        int row = t & 31, seg = t >> 5;
        const float* fr = feat_mac + ((size_t)b * N_MAC + m0 + row) * DIM + seg * 8;
        float p = 0.f;
        #pragma unroll
        for (int k = 0; k < 8; ++k) p = fmaf(fr[k], waS[seg * 8 + k], p);
        buf1[seg * 32 + row] = p;
    }
    __syncthreads();
    if (t < 32) {
        float s = 0.f;
        #pragma unroll
        for (int sg = 0; sg < 8; ++sg) s += buf1[sg * 32 + t];
        amS[t] = s;
    }
    __syncthreads();

    float am0 = amS[L], am1 = amS[16 + L];
    float pM0 = __expf(am0), qM0 = __expf(0.2f * am0);
    float pM1 = __expf(am1), qM1 = __expf(0.2f * am1);

    const int* adjt = adj + (size_t)bidx[b] * N_OPE * N_MAC;
    const unsigned short* htb = h_t + (size_t)b * KOUT * N_OPE;
    const float2* pqb = pq + (size_t)b * N_OPE;

    floatx4 C0[8], C1[8];
    #pragma unroll
    for (int i = 0; i < 8; ++i) { C0[i] = (floatx4)0.f; C1[i] = (floatx4)0.f; }
    float den0 = 0.f, den1 = 0.f;

    int oBeg = wv * (N_OPE / 4);
    for (int o0 = oBeg; o0 < oBeg + N_OPE / 4; o0 += 32) {
        int ob = o0 + q * 8;
        float4 pv0 = *(const float4*)(pqb + ob);
        float4 pv1 = *(const float4*)(pqb + ob + 2);
        float4 pv2 = *(const float4*)(pqb + ob + 4);
        float4 pv3 = *(const float4*)(pqb + ob + 6);
        float pA[8] = {pv0.x, pv0.z, pv1.x, pv1.z, pv2.x, pv2.z, pv3.x, pv3.z};
        float qA[8] = {pv0.y, pv0.w, pv1.y, pv1.w, pv2.y, pv2.w, pv3.y, pv3.w};

        short8 Bf[8];
        #pragma unroll
        for (int nf = 0; nf < 8; ++nf)
            Bf[nf] = *(const short8*)(htb + (size_t)(nf * 16 + L) * N_OPE + ob);

        int mk0[8], mk1[8];
        #pragma unroll
        for (int j = 0; j < 8; ++j) {
            mk0[j] = adjt[(size_t)(ob + j) * N_MAC + m0 + L];
            mk1[j] = adjt[(size_t)(ob + j) * N_MAC + m0 + 16 + L];
        }

        float w0v[8], w1v[8];
        #pragma unroll
        for (int j = 0; j < 8; ++j) {
            float tp0 = pA[j] * pM0;
            float w0 = (tp0 >= 1.0f) ? tp0 : qA[j] * qM0;
            w0 = (mk0[j] == 1) ? w0 : 0.f;
            den0 += w0; w0v[j] = w0;
            float tp1 = pA[j] * pM1;
            float w1 = (tp1 >= 1.0f) ? tp1 : qA[j] * qM1;
            w1 = (mk1[j] == 1) ? w1 : 0.f;
            den1 += w1; w1v[j] = w1;
        }
        int4 A0i, A1i;
        #pragma unroll
        for (int j2 = 0; j2 < 4; ++j2) {
            unsigned lo0 = __builtin_bit_cast(unsigned, w0v[2 * j2])     + 0x8000u;
            unsigned hi0 = __builtin_bit_cast(unsigned, w0v[2 * j2 + 1]) + 0x8000u;
            ((unsigned*)&A0i)[j2] = __builtin_amdgcn_perm(hi0, lo0, 0x07060302u);
            unsigned lo1 = __builtin_bit_cast(unsigned, w1v[2 * j2])     + 0x8000u;
            unsigned hi1 = __builtin_bit_cast(unsigned, w1v[2 * j2 + 1]) + 0x8000u;
            ((unsigned*)&A1i)[j2] = __builtin_amdgcn_perm(hi1, lo1, 0x07060302u);
        }
        short8 A0 = __builtin_bit_cast(short8, A0i);
        short8 A1 = __builtin_bit_cast(short8, A1i);

        #pragma unroll
        for (int nf = 0; nf < 8; ++nf) {
            C0[nf] = __builtin_amdgcn_mfma_f32_16x16x32_bf16(A0, Bf[nf], C0[nf], 0, 0, 0);
            C1[nf] = __builtin_amdgcn_mfma_f32_16x16x32_bf16(A1, Bf[nf], C1[nf], 0, 0, 0);
        }
    }

    den0 += __shfl_xor(den0, 16); den0 += __shfl_xor(den0, 32);
    den1 += __shfl_xor(den1, 16); den1 += __shfl_xor(den1, 32);
    if (q == 0) { DS[wv][L] = den0; DS[wv][16 + L] = den1; }

    // ---- two-round cross-wave C reduction (stride 132: 2-way conflicts only)
    if (wv == 0 || wv == 2) {
        float* bp = (wv == 0) ? buf0 : buf1;
        #pragma unroll
        for (int mf = 0; mf < 2; ++mf) {
            const floatx4* Cf = mf ? C1 : C0;
            #pragma unroll
            for (int nf = 0; nf < 8; ++nf)
                #pragma unroll
                for (int r = 0; r < 4; ++r)
                    bp[(mf * 16 + q * 4 + r) * 132 + nf * 16 + L] = Cf[nf][r];
        }
    }
    __syncthreads();
    if (wv == 1 || wv == 3) {
        float* bp = (wv == 1) ? buf0 : buf1;
        #pragma unroll
        for (int mf = 0; mf < 2; ++mf) {
            const floatx4* Cf = mf ? C1 : C0;
            #pragma unroll
            for (int nf = 0; nf < 8; ++nf)
                #pragma unroll
                for (int r = 0; r < 4; ++r)
                    bp[(mf * 16 + q * 4 + r) * 132 + nf * 16 + L] += Cf[nf][r];
        }
    }
    __syncthreads();

    // ---- inline h_res = feat_mac . res_w^T (3-term split MFMA), wave handles 2 n-frags
    float fA[2][2][8];
    #pragma unroll
    for (int mf = 0; mf < 2; ++mf) {
        const float* fr = feat_mac + ((size_t)b * N_MAC + m0 + mf * 16 + L) * DIM + q * 8;
        #pragma unroll
        for (int ks = 0; ks < 2; ++ks) {
            float4 v0 = *(const float4*)(fr + ks * 32);
            float4 v1 = *(const float4*)(fr + ks * 32 + 4);
            fA[mf][ks][0] = v0.x; fA[mf][ks][1] = v0.y; fA[mf][ks][2] = v0.z; fA[mf][ks][3] = v0.w;
            fA[mf][ks][4] = v1.x; fA[mf][ks][5] = v1.y; fA[mf][ks][6] = v1.z; fA[mf][ks][7] = v1.w;
        }
    }
    short8 Ah[2][2], Al[2][2];
    #pragma unroll
    for (int mf = 0; mf < 2; ++mf)
        #pragma unroll
        for (int ks = 0; ks < 2; ++ks)
            #pragma unroll
            for (int j = 0; j < 8; ++j) {
                float x = fA[mf][ks][j];
                unsigned short h = f2bf(x);
                Ah[mf][ks][j] = (short)h;
                Al[mf][ks][j] = (short)f2bf(x - bf2f(h));
            }
    floatx4 R[2][2];
    R[0][0] = (floatx4)0.f; R[0][1] = (floatx4)0.f;
    R[1][0] = (floatx4)0.f; R[1][1] = (floatx4)0.f;
    #pragma unroll
    for (int ks = 0; ks < 2; ++ks) {
        #pragma unroll
        for (int nfl = 0; nfl < 2; ++nfl) {
            const float* wp = res_w + (size_t)((wv * 2 + nfl) * 16 + L) * DIM + ks * 32 + q * 8;
            float4 u0 = *(const float4*)(wp);
            float4 u1 = *(const float4*)(wp + 4);
            float bw[8] = {u0.x, u0.y, u0.z, u0.w, u1.x, u1.y, u1.z, u1.w};
            short8 Bh, Bl;
            #pragma unroll
            for (int j = 0; j < 8; ++j) {
                unsigned short h = f2bf(bw[j]);
                Bh[j] = (short)h;
                Bl[j] = (short)f2bf(bw[j] - bf2f(h));
            }
            #pragma unroll
            for (int mf = 0; mf < 2; ++mf) {
                R[mf][nfl] = __builtin_amdgcn_mfma_f32_16x16x32_bf16(Ah[mf][ks], Bh, R[mf][nfl], 0, 0, 0);
                R[mf][nfl] = __builtin_amdgcn_mfma_f32_16x16x32_bf16(Al[mf][ks], Bh, R[mf][nfl], 0, 0, 0);
                R[mf][nfl] = __builtin_amdgcn_mfma_f32_16x16x32_bf16(Ah[mf][ks], Bl, R[mf][nfl], 0, 0, 0);
            }
        }
    }

    // ---- epilogue: divide, add h_res, store (wave covers its 2 n-frags)
    #pragma unroll
    for (int mf = 0; mf < 2; ++mf) {
        #pragma unroll
        for (int r = 0; r < 4; ++r) {
            int row = mf * 16 + q * 4 + r;
            float inv = 1.0f / (DS[0][row] + DS[1][row] + DS[2][row] + DS[3][row]);
            size_t obase = ((size_t)b * N_MAC + m0 + row) * KOUT;
            #pragma unroll
            for (int nfl = 0; nfl < 2; ++nfl) {
                int col = (wv * 2 + nfl) * 16 + L;
                out[obase + col] = (buf0[row * 132 + col] + buf1[row * 132 + col]) * inv
                                   + R[mf][nfl][r];
            }
        }
    }
}

extern "C" void kernel_launch(void* const* d_in, const int* in_sizes, int n_in,
                              void* d_out, int out_size, void* d_ws, size_t ws_size,
                              hipStream_t stream) {
    const int*   adj       = (const int*)d_in[0];
    const int*   bidx      = (const int*)d_in[1];
    const float* feat_ope  = (const float*)d_in[2];
    const float* feat_mac  = (const float*)d_in[3];
    const float* ope_w     = (const float*)d_in[4];
    const float* mac_w     = (const float*)d_in[5];
    const float* ope_alpha = (const float*)d_in[6];
    const float* mac_alpha = (const float*)d_in[7];
    const float* res_w     = (const float*)d_in[8];
    float* out = (float*)d_out;

    char* ws = (char*)d_ws;
    unsigned short* h_t = (unsigned short*)ws;                // 16 MiB bf16 [B][128][2048]
    float2* pq          = (float2*)(ws + (size_t)(16 << 20)); // 512 KiB [B][2048] (expA, expA^0.2)

    k_ope<<<512, 256, 0, stream>>>(feat_ope, ope_w, ope_alpha, h_t, pq);
    k_attn<<<dim3(N_MAC / 32, NB), 256, 0, stream>>>(adj, bidx, h_t, pq, feat_mac,
                                                     mac_w, mac_alpha, res_w, out);
}